// Round 2
// baseline (122.902 us; speedup 1.0000x reference)
//
#include <hip/hip_runtime.h>
#include <hip/hip_bf16.h>

#define B_ROWS 4096
#define C_CLS  1000
#define D_DIM  2048
#define NPAD   1024

typedef __attribute__((ext_vector_type(8))) short s16x8;
typedef __attribute__((ext_vector_type(4))) float f32x4;

__device__ __forceinline__ unsigned short f2bf(float f) {
    __hip_bfloat16 h = __float2bfloat16(f);
    unsigned short u;
    __builtin_memcpy(&u, &h, 2);
    return u;
}

// Kernel 1: W (1000x2048 fp32) -> Wb (1024x2048 bf16, padded rows zero) + sq_w fp32
__global__ __launch_bounds__(256) void prep_kernel(const float* __restrict__ W,
                                                   unsigned short* __restrict__ Wb,
                                                   float* __restrict__ sqw) {
    const int row = blockIdx.x;
    const int tid = threadIdx.x;
    unsigned short* wrow = Wb + (size_t)row * D_DIM;
    if (row >= C_CLS) {
        uint4 z; z.x = z.y = z.z = z.w = 0u;
        *reinterpret_cast<uint4*>(wrow + tid * 8) = z;
        if (tid == 0) sqw[row] = 0.f;
        return;
    }
    const float* wr = W + (size_t)row * D_DIM;
    float4 x0 = *reinterpret_cast<const float4*>(wr + tid * 8);
    float4 x1 = *reinterpret_cast<const float4*>(wr + tid * 8 + 4);
    float s = x0.x * x0.x + x0.y * x0.y + x0.z * x0.z + x0.w * x0.w
            + x1.x * x1.x + x1.y * x1.y + x1.z * x1.z + x1.w * x1.w;
    union { unsigned short u[8]; uint4 v; } pk;
    pk.u[0] = f2bf(x0.x); pk.u[1] = f2bf(x0.y); pk.u[2] = f2bf(x0.z); pk.u[3] = f2bf(x0.w);
    pk.u[4] = f2bf(x1.x); pk.u[5] = f2bf(x1.y); pk.u[6] = f2bf(x1.z); pk.u[7] = f2bf(x1.w);
    *reinterpret_cast<uint4*>(wrow + tid * 8) = pk.v;
#pragma unroll
    for (int off = 32; off > 0; off >>= 1) s += __shfl_down(s, off);
    __shared__ float sv[4];
    const int lane = tid & 63, wid = tid >> 6;
    if (lane == 0) sv[wid] = s;
    __syncthreads();
    if (tid == 0) sqw[row] = sv[0] + sv[1] + sv[2] + sv[3];
}

// Kernel 2: dist[a][c] = k * sqrt(max(sq[a]+sq[c]-2*Wb[a].Wb[c], 0))
// Upper-triangular 32x32 tiles (528 blocks), 256 thr (4 waves), one 16x16 MFMA
// quadrant per wave, 2-deep k-ILP, mirror stores for the lower triangle.
// Symmetric pairs are bitwise-identical (same dot product, same k-order), so
// symmetry-exploitation is exact.
__global__ __launch_bounds__(256) void dist_kernel(const unsigned short* __restrict__ Wb,
                                                   const float* __restrict__ sqw,
                                                   const float* __restrict__ Kin,
                                                   float* __restrict__ dist) {
    const int tid  = threadIdx.x;
    const int lane = tid & 63;
    const int wid  = tid >> 6;       // 0..3
    const int wm   = wid >> 1;       // 0..1
    const int wn   = wid & 1;        // 0..1
    const int l16  = lane & 15;
    const int quad = lane >> 4;      // 0..3

    // closed-form decode: linear block id -> (by, bx), bx >= by, 32 tiles/dim.
    // offset(by) = by*(65-by)/2; discriminant at boundaries is (65-2*by)^2 (exact).
    const int t = blockIdx.x;
    int by = (int)((65.0f - sqrtf((float)(4225 - 8 * t))) * 0.5f);
    // guard against fp rounding at tile boundaries
    while (by * (65 - by) / 2 > t) --by;
    while ((by + 1) * (65 - (by + 1)) / 2 <= t) ++by;
    const int bx = by + (t - by * (65 - by) / 2);

    const int base_m = by * 32 + wm * 16;
    const int base_n = bx * 32 + wn * 16;

    f32x4 acc0 = {0.f, 0.f, 0.f, 0.f};
    f32x4 acc1 = {0.f, 0.f, 0.f, 0.f};

    const unsigned short* arow = Wb + (size_t)(base_m + l16) * D_DIM;
    const unsigned short* brow = Wb + (size_t)(base_n + l16) * D_DIM;

    for (int k = 0; k < D_DIM; k += 64) {
        const int kk = k + quad * 8;
        s16x8 a0 = *reinterpret_cast<const s16x8*>(arow + kk);
        s16x8 b0 = *reinterpret_cast<const s16x8*>(brow + kk);
        s16x8 a1 = *reinterpret_cast<const s16x8*>(arow + kk + 32);
        s16x8 b1 = *reinterpret_cast<const s16x8*>(brow + kk + 32);
        acc0 = __builtin_amdgcn_mfma_f32_16x16x32_bf16(a0, b0, acc0, 0, 0, 0);
        acc1 = __builtin_amdgcn_mfma_f32_16x16x32_bf16(a1, b1, acc1, 0, 0, 0);
    }
    f32x4 acc = acc0 + acc1;

    const float kscale = Kin[0] * 4.4642857142857144f;  // 1/0.224 (DATA_SCALING)

#pragma unroll
    for (int r = 0; r < 4; ++r) {
        const int ga = base_m + quad * 4 + r;   // C/D: row = quad*4+reg
        const int gc = base_n + l16;            // C/D: col = lane&15
        float d2 = sqw[ga] + sqw[gc] - 2.0f * acc[r];
        float v = kscale * sqrtf(fmaxf(d2, 0.f));
        dist[(size_t)ga * NPAD + gc] = v;
        if (bx != by) dist[(size_t)gc * NPAD + ga] = v;
    }
}

// Kernel 3: per row of prediction: argmax (lowest-index tie-break) then min ratio
__global__ __launch_bounds__(256) void final_kernel(const float* __restrict__ pred,
                                                    const float* __restrict__ dist,
                                                    float* __restrict__ out) {
    const int row = blockIdx.x;
    const int tid = threadIdx.x;
    const int lane = tid & 63, wid = tid >> 6;
    __shared__ float sp[C_CLS];
    __shared__ float sv[4];
    __shared__ int   si[4];

    const float* p = pred + (size_t)row * C_CLS;
    float v = -INFINITY;
    int bi = 0x7fffffff;
    if (tid < 250) {  // 250*4 = 1000, 16B aligned (row stride 4000 B is 16B-multiple)
        float4 x = *reinterpret_cast<const float4*>(p + tid * 4);
        const int c0 = tid * 4;
        sp[c0 + 0] = x.x; sp[c0 + 1] = x.y; sp[c0 + 2] = x.z; sp[c0 + 3] = x.w;
        v = x.x; bi = c0;
        if (x.y > v) { v = x.y; bi = c0 + 1; }
        if (x.z > v) { v = x.z; bi = c0 + 2; }
        if (x.w > v) { v = x.w; bi = c0 + 3; }
    }
#pragma unroll
    for (int off = 32; off > 0; off >>= 1) {
        float ov = __shfl_down(v, off);
        int   oi = __shfl_down(bi, off);
        if (ov > v || (ov == v && oi < bi)) { v = ov; bi = oi; }
    }
    if (lane == 0) { sv[wid] = v; si[wid] = bi; }
    __syncthreads();
    float y0 = sv[0]; int j0 = si[0];
#pragma unroll
    for (int w = 1; w < 4; ++w) {
        if (sv[w] > y0 || (sv[w] == y0 && si[w] < j0)) { y0 = sv[w]; j0 = si[w]; }
    }

    const float* drow = dist + (size_t)j0 * NPAD;
    float rmin = INFINITY;
    for (int c = tid; c < C_CLS; c += 256) {
        if (c == j0) continue;
        float m = y0 - sp[c];
        rmin = fminf(rmin, m / drow[c]);
    }
#pragma unroll
    for (int off = 32; off > 0; off >>= 1) rmin = fminf(rmin, __shfl_down(rmin, off));
    __syncthreads();  // all reads of sv/si for argmax done before reuse
    if (lane == 0) sv[wid] = rmin;
    __syncthreads();
    if (tid == 0) out[row] = fminf(fminf(sv[0], sv[1]), fminf(sv[2], sv[3]));
}

extern "C" void kernel_launch(void* const* d_in, const int* in_sizes, int n_in,
                              void* d_out, int out_size, void* d_ws, size_t ws_size,
                              hipStream_t stream) {
    const float* pred = (const float*)d_in[0];   // (4096, 1000) fp32
    const float* W    = (const float*)d_in[1];   // (1000, 2048) fp32
    const float* K    = (const float*)d_in[2];   // (1,) fp32
    float* out = (float*)d_out;                  // (4096,) fp32

    char* ws = (char*)d_ws;
    unsigned short* Wb = (unsigned short*)ws;                               // 1024*2048*2 = 4 MB
    float* dist = (float*)(ws + (size_t)NPAD * D_DIM * 2);                  // 1024*1024*4 = 4 MB
    float* sqw  = (float*)(ws + (size_t)NPAD * D_DIM * 2 + (size_t)NPAD * NPAD * 4); // 4 KB

    prep_kernel<<<NPAD, 256, 0, stream>>>(W, Wb, sqw);
    dist_kernel<<<528, 256, 0, stream>>>(Wb, sqw, K, dist);   // 32x32 upper-tri tiles
    final_kernel<<<B_ROWS, 256, 0, stream>>>(pred, dist, out);
}

// Round 3
// 94.857 us; speedup vs baseline: 1.2956x; 1.2956x over previous
//
#include <hip/hip_runtime.h>
#include <hip/hip_bf16.h>

#define B_ROWS 4096
#define C_CLS  1000
#define D_DIM  2048
#define NPAD   1024

typedef __attribute__((ext_vector_type(8))) short s16x8;
typedef __attribute__((ext_vector_type(4))) float f32x4;

__device__ __forceinline__ unsigned short f2bf(float f) {
    __hip_bfloat16 h = __float2bfloat16(f);
    unsigned short u;
    __builtin_memcpy(&u, &h, 2);
    return u;
}

// Kernel 1: W (1000x2048 fp32) -> Wb (1024x2048 bf16, padded rows zero) + sq_w fp32
__global__ __launch_bounds__(256) void prep_kernel(const float* __restrict__ W,
                                                   unsigned short* __restrict__ Wb,
                                                   float* __restrict__ sqw) {
    const int row = blockIdx.x;
    const int tid = threadIdx.x;
    unsigned short* wrow = Wb + (size_t)row * D_DIM;
    if (row >= C_CLS) {
        uint4 z; z.x = z.y = z.z = z.w = 0u;
        *reinterpret_cast<uint4*>(wrow + tid * 8) = z;
        if (tid == 0) sqw[row] = 0.f;
        return;
    }
    const float* wr = W + (size_t)row * D_DIM;
    float4 x0 = *reinterpret_cast<const float4*>(wr + tid * 8);
    float4 x1 = *reinterpret_cast<const float4*>(wr + tid * 8 + 4);
    float s = x0.x * x0.x + x0.y * x0.y + x0.z * x0.z + x0.w * x0.w
            + x1.x * x1.x + x1.y * x1.y + x1.z * x1.z + x1.w * x1.w;
    union { unsigned short u[8]; uint4 v; } pk;
    pk.u[0] = f2bf(x0.x); pk.u[1] = f2bf(x0.y); pk.u[2] = f2bf(x0.z); pk.u[3] = f2bf(x0.w);
    pk.u[4] = f2bf(x1.x); pk.u[5] = f2bf(x1.y); pk.u[6] = f2bf(x1.z); pk.u[7] = f2bf(x1.w);
    *reinterpret_cast<uint4*>(wrow + tid * 8) = pk.v;
#pragma unroll
    for (int off = 32; off > 0; off >>= 1) s += __shfl_down(s, off);
    __shared__ float sv[4];
    const int lane = tid & 63, wid = tid >> 6;
    if (lane == 0) sv[wid] = s;
    __syncthreads();
    if (tid == 0) sqw[row] = sv[0] + sv[1] + sv[2] + sv[3];
}

// Kernel 2: dist[a][c] = k * sqrt(max(sq[a]+sq[c]-2*Wb[a].Wb[c], 0))
// Staged GEMM, 2-phase double-buffered LDS (T3-minimum template):
//   grid 16x16 tiles of 64x64 (256 blocks = 1/CU, uniform), 512 thr = 8 waves,
//   wave (wm,wn) = (wid>>1, wid&1) owns a 16x32 sub-tile (1x2 MFMA 16x16x32).
//   global_load_lds width-16 staging, 16B-granule XOR swizzle applied on BOTH
//   sides (pre-swizzled global source + swizzled ds_read) per rule #21.
__global__ __launch_bounds__(512) void dist_kernel(const unsigned short* __restrict__ Wb,
                                                   const float* __restrict__ sqw,
                                                   const float* __restrict__ Kin,
                                                   float* __restrict__ dist) {
    __shared__ unsigned short smem[2][2][64 * 64];   // [buf][A/B][row*64+col], 32 KB

    const int tid  = threadIdx.x;
    const int lane = tid & 63;
    const int wid  = tid >> 6;        // 0..7
    const int wm   = wid >> 1;        // 0..3  (16-row strip)
    const int wn   = wid & 1;         // 0..1  (32-col strip)
    const int l16  = lane & 15;
    const int quad = lane >> 4;       // 0..3

    // XCD-locality swizzle: 8 regions of 4(by) x 8(bx) tiles; XCD key = blockIdx & 7
    const int b  = blockIdx.x;
    const int rg = b & 7, s = b >> 3;
    const int by = (rg >> 1) * 4 + (s >> 3);   // 0..15
    const int bx = (rg & 1) * 8 + (s & 7);     // 0..15

    // staging: wave wid covers tile rows [wid*8, wid*8+8), 64 cols (128 B) per k-step.
    // LDS dest is linear (wave-uniform base + lane*16); the XOR swizzle
    // (byte ^= (row&7)<<4) is realized by permuting the GLOBAL source column:
    //   row-in-8 = lane>>3, granule = (lane&7) ^ (lane>>3)
    const int srow = wid * 8 + (lane >> 3);
    const int scol = (((lane & 7) ^ (lane >> 3)) << 3);   // elements (granule*8)
    const unsigned short* gA = Wb + (size_t)(by * 64 + srow) * D_DIM + scol;
    const unsigned short* gB = Wb + (size_t)(bx * 64 + srow) * D_DIM + scol;

#define STAGE(bufi, kk)                                                                 \
    do {                                                                                \
        __builtin_amdgcn_global_load_lds(                                               \
            (const __attribute__((address_space(1))) void*)(gA + (kk)),                 \
            (__attribute__((address_space(3))) void*)&smem[bufi][0][wid * 512], 16, 0, 0); \
        __builtin_amdgcn_global_load_lds(                                               \
            (const __attribute__((address_space(1))) void*)(gB + (kk)),                 \
            (__attribute__((address_space(3))) void*)&smem[bufi][1][wid * 512], 16, 0, 0); \
    } while (0)

    f32x4 acc0 = {0.f, 0.f, 0.f, 0.f};
    f32x4 acc1 = {0.f, 0.f, 0.f, 0.f};

    STAGE(0, 0);
    __syncthreads();   // drains vmcnt(0): buf0 ready

    const int arow = (wm * 16 + l16) * 64;
    const int brow0 = (wn * 32 + l16) * 64;
    const int brow1 = (wn * 32 + 16 + l16) * 64;

    for (int t = 0; t < 32; ++t) {
        const int cur = t & 1;
        if (t < 31) STAGE(cur ^ 1, (t + 1) * 64);   // prefetch next k-tile (overlaps compute)

        const unsigned short* Ab = &smem[cur][0][0];
        const unsigned short* Bb = &smem[cur][1][0];
        s16x8 a[2], b0[2], b1[2];
#pragma unroll
        for (int ks = 0; ks < 2; ++ks) {
            // swizzled read: col-granule (ks*4+quad) ^ (lane&7), *16B (=8 elements)
            const int cs = ((((ks << 2) | quad) ^ (lane & 7)) << 3);
            a[ks]  = *reinterpret_cast<const s16x8*>(Ab + arow  + cs);
            b0[ks] = *reinterpret_cast<const s16x8*>(Bb + brow0 + cs);
            b1[ks] = *reinterpret_cast<const s16x8*>(Bb + brow1 + cs);
        }
#pragma unroll
        for (int ks = 0; ks < 2; ++ks) {
            acc0 = __builtin_amdgcn_mfma_f32_16x16x32_bf16(a[ks], b0[ks], acc0, 0, 0, 0);
            acc1 = __builtin_amdgcn_mfma_f32_16x16x32_bf16(a[ks], b1[ks], acc1, 0, 0, 0);
        }
        __syncthreads();   // vmcnt(0)+lgkmcnt(0)+barrier: next buf staged, cur buf free
    }
#undef STAGE

    const float kscale = Kin[0] * 4.4642857142857144f;  // 1/0.224 (DATA_SCALING)

    f32x4 accs[2] = {acc0, acc1};
#pragma unroll
    for (int nt = 0; nt < 2; ++nt) {
#pragma unroll
        for (int r = 0; r < 4; ++r) {
            const int ga = by * 64 + wm * 16 + quad * 4 + r;   // C/D: row = quad*4+reg
            const int gc = bx * 64 + wn * 32 + nt * 16 + l16;  // C/D: col = lane&15
            float d2 = sqw[ga] + sqw[gc] - 2.0f * accs[nt][r];
            dist[(size_t)ga * NPAD + gc] = kscale * sqrtf(fmaxf(d2, 0.f));
        }
    }
}

// Kernel 3: per row of prediction: argmax (lowest-index tie-break) then min ratio
__global__ __launch_bounds__(256) void final_kernel(const float* __restrict__ pred,
                                                    const float* __restrict__ dist,
                                                    float* __restrict__ out) {
    const int row = blockIdx.x;
    const int tid = threadIdx.x;
    const int lane = tid & 63, wid = tid >> 6;
    __shared__ float sp[C_CLS];
    __shared__ float sv[4];
    __shared__ int   si[4];

    const float* p = pred + (size_t)row * C_CLS;
    float v = -INFINITY;
    int bi = 0x7fffffff;
    if (tid < 250) {  // 250*4 = 1000, 16B aligned (row stride 4000 B is 16B-multiple)
        float4 x = *reinterpret_cast<const float4*>(p + tid * 4);
        const int c0 = tid * 4;
        sp[c0 + 0] = x.x; sp[c0 + 1] = x.y; sp[c0 + 2] = x.z; sp[c0 + 3] = x.w;
        v = x.x; bi = c0;
        if (x.y > v) { v = x.y; bi = c0 + 1; }
        if (x.z > v) { v = x.z; bi = c0 + 2; }
        if (x.w > v) { v = x.w; bi = c0 + 3; }
    }
#pragma unroll
    for (int off = 32; off > 0; off >>= 1) {
        float ov = __shfl_down(v, off);
        int   oi = __shfl_down(bi, off);
        if (ov > v || (ov == v && oi < bi)) { v = ov; bi = oi; }
    }
    if (lane == 0) { sv[wid] = v; si[wid] = bi; }
    __syncthreads();
    float y0 = sv[0]; int j0 = si[0];
#pragma unroll
    for (int w = 1; w < 4; ++w) {
        if (sv[w] > y0 || (sv[w] == y0 && si[w] < j0)) { y0 = sv[w]; j0 = si[w]; }
    }

    const float* drow = dist + (size_t)j0 * NPAD;
    float rmin = INFINITY;
    for (int c = tid; c < C_CLS; c += 256) {
        if (c == j0) continue;
        float m = y0 - sp[c];
        rmin = fminf(rmin, m / drow[c]);
    }
#pragma unroll
    for (int off = 32; off > 0; off >>= 1) rmin = fminf(rmin, __shfl_down(rmin, off));
    __syncthreads();  // all reads of sv/si for argmax done before reuse
    if (lane == 0) sv[wid] = rmin;
    __syncthreads();
    if (tid == 0) out[row] = fminf(fminf(sv[0], sv[1]), fminf(sv[2], sv[3]));
}

extern "C" void kernel_launch(void* const* d_in, const int* in_sizes, int n_in,
                              void* d_out, int out_size, void* d_ws, size_t ws_size,
                              hipStream_t stream) {
    const float* pred = (const float*)d_in[0];   // (4096, 1000) fp32
    const float* W    = (const float*)d_in[1];   // (1000, 2048) fp32
    const float* K    = (const float*)d_in[2];   // (1,) fp32
    float* out = (float*)d_out;                  // (4096,) fp32

    char* ws = (char*)d_ws;
    unsigned short* Wb = (unsigned short*)ws;                               // 1024*2048*2 = 4 MB
    float* dist = (float*)(ws + (size_t)NPAD * D_DIM * 2);                  // 1024*1024*4 = 4 MB
    float* sqw  = (float*)(ws + (size_t)NPAD * D_DIM * 2 + (size_t)NPAD * NPAD * 4); // 4 KB

    prep_kernel<<<NPAD, 256, 0, stream>>>(W, Wb, sqw);
    dist_kernel<<<dim3(256), 512, 0, stream>>>(Wb, sqw, K, dist);
    final_kernel<<<B_ROWS, 256, 0, stream>>>(pred, dist, out);
}

// Round 4
// 88.106 us; speedup vs baseline: 1.3949x; 1.0766x over previous
//
#include <hip/hip_runtime.h>
#include <hip/hip_bf16.h>

#define B_ROWS 4096
#define C_CLS  1000
#define D_DIM  2048
#define NPAD   1024

typedef __attribute__((ext_vector_type(8))) short s16x8;
typedef __attribute__((ext_vector_type(4))) float f32x4;

__device__ __forceinline__ unsigned short f2bf(float f) {
    __hip_bfloat16 h = __float2bfloat16(f);
    unsigned short u;
    __builtin_memcpy(&u, &h, 2);
    return u;
}

// Kernel 1: W (1000x2048 fp32) -> Wb (1024x2048 bf16, padded rows zero) + sq_w fp32
__global__ __launch_bounds__(256) void prep_kernel(const float* __restrict__ W,
                                                   unsigned short* __restrict__ Wb,
                                                   float* __restrict__ sqw) {
    const int row = blockIdx.x;
    const int tid = threadIdx.x;
    unsigned short* wrow = Wb + (size_t)row * D_DIM;
    if (row >= C_CLS) {
        uint4 z; z.x = z.y = z.z = z.w = 0u;
        *reinterpret_cast<uint4*>(wrow + tid * 8) = z;
        if (tid == 0) sqw[row] = 0.f;
        return;
    }
    const float* wr = W + (size_t)row * D_DIM;
    float4 x0 = *reinterpret_cast<const float4*>(wr + tid * 8);
    float4 x1 = *reinterpret_cast<const float4*>(wr + tid * 8 + 4);
    float s = x0.x * x0.x + x0.y * x0.y + x0.z * x0.z + x0.w * x0.w
            + x1.x * x1.x + x1.y * x1.y + x1.z * x1.z + x1.w * x1.w;
    union { unsigned short u[8]; uint4 v; } pk;
    pk.u[0] = f2bf(x0.x); pk.u[1] = f2bf(x0.y); pk.u[2] = f2bf(x0.z); pk.u[3] = f2bf(x0.w);
    pk.u[4] = f2bf(x1.x); pk.u[5] = f2bf(x1.y); pk.u[6] = f2bf(x1.z); pk.u[7] = f2bf(x1.w);
    *reinterpret_cast<uint4*>(wrow + tid * 8) = pk.v;
#pragma unroll
    for (int off = 32; off > 0; off >>= 1) s += __shfl_down(s, off);
    __shared__ float sv[4];
    const int lane = tid & 63, wid = tid >> 6;
    if (lane == 0) sv[wid] = s;
    __syncthreads();
    if (tid == 0) sqw[row] = sv[0] + sv[1] + sv[2] + sv[3];
}

// Kernel 2: dist[a][c] = k * sqrt(max(sq[a]+sq[c]-2*Wb[a].Wb[c], 0))
// Staged GEMM with T4 counted-vmcnt pipeline: 3 LDS buffers, prefetch depth 2,
// raw s_barrier (no vmcnt(0) drain in steady state).
//   grid 16x16 tiles of 64x64 (256 blocks), 512 thr = 8 waves,
//   wave (wm,wn) owns a 16x32 sub-tile (1x2 MFMA 16x16x32).
//   global_load_lds width-16 staging; 16B-granule XOR swizzle applied on BOTH
//   sides (pre-swizzled global source + swizzled ds_read) per rule #21.
// Race analysis: step t = [vmcnt(2): own S(t) done] -> [barrier: ALL waves' S(t)
// done, all reads of buf (t-1)%3 done] -> [issue S(t+2) into (t+2)%3 = (t-1)%3:
// safe] -> [ds_read buf t%3 + MFMA]. Last step waits vmcnt(0).
__global__ __launch_bounds__(512) void dist_kernel(const unsigned short* __restrict__ Wb,
                                                   const float* __restrict__ sqw,
                                                   const float* __restrict__ Kin,
                                                   float* __restrict__ dist) {
    __shared__ unsigned short smem[3][2][64 * 64];   // [buf][A/B][row*64+col], 48 KB

    const int tid  = threadIdx.x;
    const int lane = tid & 63;
    const int wid  = tid >> 6;        // 0..7
    const int wm   = wid >> 1;        // 0..3  (16-row strip)
    const int wn   = wid & 1;         // 0..1  (32-col strip)
    const int l16  = lane & 15;
    const int quad = lane >> 4;       // 0..3

    // XCD-locality swizzle: 8 regions of 4(by) x 8(bx) tiles; XCD key = blockIdx & 7
    const int b  = blockIdx.x;
    const int rg = b & 7, s = b >> 3;
    const int by = (rg >> 1) * 4 + (s >> 3);   // 0..15
    const int bx = (rg & 1) * 8 + (s & 7);     // 0..15

    // staging: wave wid covers tile rows [wid*8, wid*8+8), 64 cols (128 B) per k-step.
    // LDS dest linear (wave base + lane*16); XOR swizzle (byte ^= (row&7)<<4)
    // realized by permuting the GLOBAL source granule: (lane&7) ^ (lane>>3).
    const int srow = wid * 8 + (lane >> 3);
    const int scol = (((lane & 7) ^ (lane >> 3)) << 3);   // elements (granule*8)
    const unsigned short* gA = Wb + (size_t)(by * 64 + srow) * D_DIM + scol;
    const unsigned short* gB = Wb + (size_t)(bx * 64 + srow) * D_DIM + scol;

#define STAGE(bufi, kk)                                                                 \
    do {                                                                                \
        __builtin_amdgcn_global_load_lds(                                               \
            (const __attribute__((address_space(1))) void*)(gA + (kk)),                 \
            (__attribute__((address_space(3))) void*)&smem[bufi][0][wid * 512], 16, 0, 0); \
        __builtin_amdgcn_global_load_lds(                                               \
            (const __attribute__((address_space(1))) void*)(gB + (kk)),                 \
            (__attribute__((address_space(3))) void*)&smem[bufi][1][wid * 512], 16, 0, 0); \
    } while (0)

    f32x4 acc0 = {0.f, 0.f, 0.f, 0.f};
    f32x4 acc1 = {0.f, 0.f, 0.f, 0.f};

    STAGE(0, 0);
    STAGE(1, 64);

    const int arow  = (wm * 16 + l16) * 64;
    const int brow0 = (wn * 32 + l16) * 64;
    const int brow1 = (wn * 32 + 16 + l16) * 64;

    for (int t = 0; t < 32; ++t) {
        // wait own S(t) (leave S(t+1) in flight), then sync all waves
        if (t < 31) asm volatile("s_waitcnt vmcnt(2)" ::: "memory");
        else        asm volatile("s_waitcnt vmcnt(0)" ::: "memory");
        __builtin_amdgcn_s_barrier();
        asm volatile("" ::: "memory");

        if (t < 30) STAGE((t + 2) % 3, (t + 2) * 64);   // into slot (t-1)%3: free now

        const unsigned short* Ab = &smem[t % 3][0][0];
        const unsigned short* Bb = &smem[t % 3][1][0];
        s16x8 a[2], b0[2], b1[2];
#pragma unroll
        for (int ks = 0; ks < 2; ++ks) {
            // swizzled read: col-granule (ks*4+quad) ^ (row&7), row&7 == lane&7 here
            const int cs = ((((ks << 2) | quad) ^ (lane & 7)) << 3);
            a[ks]  = *reinterpret_cast<const s16x8*>(Ab + arow  + cs);
            b0[ks] = *reinterpret_cast<const s16x8*>(Bb + brow0 + cs);
            b1[ks] = *reinterpret_cast<const s16x8*>(Bb + brow1 + cs);
        }
#pragma unroll
        for (int ks = 0; ks < 2; ++ks) {
            acc0 = __builtin_amdgcn_mfma_f32_16x16x32_bf16(a[ks], b0[ks], acc0, 0, 0, 0);
            acc1 = __builtin_amdgcn_mfma_f32_16x16x32_bf16(a[ks], b1[ks], acc1, 0, 0, 0);
        }
    }
#undef STAGE

    const float kscale = Kin[0] * 4.4642857142857144f;  // 1/0.224 (DATA_SCALING)

    f32x4 accs[2] = {acc0, acc1};
#pragma unroll
    for (int nt = 0; nt < 2; ++nt) {
#pragma unroll
        for (int r = 0; r < 4; ++r) {
            const int ga = by * 64 + wm * 16 + quad * 4 + r;   // C/D: row = quad*4+reg
            const int gc = bx * 64 + wn * 32 + nt * 16 + l16;  // C/D: col = lane&15
            float d2 = sqw[ga] + sqw[gc] - 2.0f * accs[nt][r];
            dist[(size_t)ga * NPAD + gc] = kscale * sqrtf(fmaxf(d2, 0.f));
        }
    }
}

// Kernel 3: per row of prediction: argmax (lowest-index tie-break) then min ratio
__global__ __launch_bounds__(256) void final_kernel(const float* __restrict__ pred,
                                                    const float* __restrict__ dist,
                                                    float* __restrict__ out) {
    const int row = blockIdx.x;
    const int tid = threadIdx.x;
    const int lane = tid & 63, wid = tid >> 6;
    __shared__ float sp[C_CLS];
    __shared__ float sv[4];
    __shared__ int   si[4];

    const float* p = pred + (size_t)row * C_CLS;
    float v = -INFINITY;
    int bi = 0x7fffffff;
    if (tid < 250) {  // 250*4 = 1000, 16B aligned (row stride 4000 B is 16B-multiple)
        float4 x = *reinterpret_cast<const float4*>(p + tid * 4);
        const int c0 = tid * 4;
        sp[c0 + 0] = x.x; sp[c0 + 1] = x.y; sp[c0 + 2] = x.z; sp[c0 + 3] = x.w;
        v = x.x; bi = c0;
        if (x.y > v) { v = x.y; bi = c0 + 1; }
        if (x.z > v) { v = x.z; bi = c0 + 2; }
        if (x.w > v) { v = x.w; bi = c0 + 3; }
    }
#pragma unroll
    for (int off = 32; off > 0; off >>= 1) {
        float ov = __shfl_down(v, off);
        int   oi = __shfl_down(bi, off);
        if (ov > v || (ov == v && oi < bi)) { v = ov; bi = oi; }
    }
    if (lane == 0) { sv[wid] = v; si[wid] = bi; }
    __syncthreads();
    float y0 = sv[0]; int j0 = si[0];
#pragma unroll
    for (int w = 1; w < 4; ++w) {
        if (sv[w] > y0 || (sv[w] == y0 && si[w] < j0)) { y0 = sv[w]; j0 = si[w]; }
    }

    const float* drow = dist + (size_t)j0 * NPAD;
    float rmin = INFINITY;
    for (int c = tid; c < C_CLS; c += 256) {
        if (c == j0) continue;
        float m = y0 - sp[c];
        // fast reciprocal (v_rcp_f32, ~2^-22 rel err — negligible vs bf16 dist error)
        rmin = fminf(rmin, m * __builtin_amdgcn_rcpf(drow[c]));
    }
#pragma unroll
    for (int off = 32; off > 0; off >>= 1) rmin = fminf(rmin, __shfl_down(rmin, off));
    __syncthreads();  // all reads of sv/si for argmax done before reuse
    if (lane == 0) sv[wid] = rmin;
    __syncthreads();
    if (tid == 0) out[row] = fminf(fminf(sv[0], sv[1]), fminf(sv[2], sv[3]));
}

extern "C" void kernel_launch(void* const* d_in, const int* in_sizes, int n_in,
                              void* d_out, int out_size, void* d_ws, size_t ws_size,
                              hipStream_t stream) {
    const float* pred = (const float*)d_in[0];   // (4096, 1000) fp32
    const float* W    = (const float*)d_in[1];   // (1000, 2048) fp32
    const float* K    = (const float*)d_in[2];   // (1,) fp32
    float* out = (float*)d_out;                  // (4096,) fp32

    char* ws = (char*)d_ws;
    unsigned short* Wb = (unsigned short*)ws;                               // 1024*2048*2 = 4 MB
    float* dist = (float*)(ws + (size_t)NPAD * D_DIM * 2);                  // 1024*1024*4 = 4 MB
    float* sqw  = (float*)(ws + (size_t)NPAD * D_DIM * 2 + (size_t)NPAD * NPAD * 4); // 4 KB

    prep_kernel<<<NPAD, 256, 0, stream>>>(W, Wb, sqw);
    dist_kernel<<<dim3(256), 512, 0, stream>>>(Wb, sqw, K, dist);
    final_kernel<<<B_ROWS, 256, 0, stream>>>(pred, dist, out);
}

// Round 5
// 87.018 us; speedup vs baseline: 1.4124x; 1.0125x over previous
//
#include <hip/hip_runtime.h>
#include <hip/hip_bf16.h>

#define B_ROWS 4096
#define C_CLS  1000
#define D_DIM  2048
#define NPAD   1024

typedef __attribute__((ext_vector_type(8))) short s16x8;
typedef __attribute__((ext_vector_type(4))) float f32x4;

__device__ __forceinline__ unsigned short f2bf(float f) {
    __hip_bfloat16 h = __float2bfloat16(f);
    unsigned short u;
    __builtin_memcpy(&u, &h, 2);
    return u;
}

// Kernel 1: W (1000x2048 fp32) -> Wb (1024x2048 bf16, padded rows zero) + sq_w fp32
__global__ __launch_bounds__(256) void prep_kernel(const float* __restrict__ W,
                                                   unsigned short* __restrict__ Wb,
                                                   float* __restrict__ sqw) {
    const int row = blockIdx.x;
    const int tid = threadIdx.x;
    unsigned short* wrow = Wb + (size_t)row * D_DIM;
    if (row >= C_CLS) {
        uint4 z; z.x = z.y = z.z = z.w = 0u;
        *reinterpret_cast<uint4*>(wrow + tid * 8) = z;
        if (tid == 0) sqw[row] = 0.f;
        return;
    }
    const float* wr = W + (size_t)row * D_DIM;
    float4 x0 = *reinterpret_cast<const float4*>(wr + tid * 8);
    float4 x1 = *reinterpret_cast<const float4*>(wr + tid * 8 + 4);
    float s = x0.x * x0.x + x0.y * x0.y + x0.z * x0.z + x0.w * x0.w
            + x1.x * x1.x + x1.y * x1.y + x1.z * x1.z + x1.w * x1.w;
    union { unsigned short u[8]; uint4 v; } pk;
    pk.u[0] = f2bf(x0.x); pk.u[1] = f2bf(x0.y); pk.u[2] = f2bf(x0.z); pk.u[3] = f2bf(x0.w);
    pk.u[4] = f2bf(x1.x); pk.u[5] = f2bf(x1.y); pk.u[6] = f2bf(x1.z); pk.u[7] = f2bf(x1.w);
    *reinterpret_cast<uint4*>(wrow + tid * 8) = pk.v;
#pragma unroll
    for (int off = 32; off > 0; off >>= 1) s += __shfl_down(s, off);
    __shared__ float sv[4];
    const int lane = tid & 63, wid = tid >> 6;
    if (lane == 0) sv[wid] = s;
    __syncthreads();
    if (tid == 0) sqw[row] = sv[0] + sv[1] + sv[2] + sv[3];
}

// Kernel 2: dist[a][c] = k * sqrt(max(sq[a]+sq[c]-2*Wb[a].Wb[c], 0))
// Staged GEMM, T4 counted-vmcnt pipeline: 4 LDS buffers, prefetch depth 3.
//   grid 16x16 tiles of 64x64 (256 blocks), 512 thr = 8 waves,
//   wave (wm,wn) owns a 16x32 sub-tile (1x2 MFMA 16x16x32).
//   global_load_lds width-16 staging; 16B-granule XOR swizzle on BOTH sides
//   (pre-swizzled global source + swizzled ds_read) per rule #21.
// Step t: [vmcnt(4): own S(t) done, S(t+1..t+2) in flight] -> [s_barrier: all
// waves' S(t) done; all step-(t-1) readers of slot (t-1)&3 done] ->
// [issue S(t+3) into slot (t+3)&3 == (t-1)&3: free] -> [ds_read slot t&3, MFMA].
// Tail: vmcnt(2) at t=30, vmcnt(0) at t=31.
__global__ __launch_bounds__(512) void dist_kernel(const unsigned short* __restrict__ Wb,
                                                   const float* __restrict__ sqw,
                                                   const float* __restrict__ Kin,
                                                   float* __restrict__ dist) {
    __shared__ unsigned short smem[4][2][64 * 64];   // [buf][A/B][row*64+col], 64 KB

    const int tid  = threadIdx.x;
    const int lane = tid & 63;
    const int wid  = tid >> 6;        // 0..7
    const int wm   = wid >> 1;        // 0..3  (16-row strip)
    const int wn   = wid & 1;         // 0..1  (32-col strip)
    const int l16  = lane & 15;
    const int quad = lane >> 4;       // 0..3

    // XCD-locality swizzle: 8 regions of 4(by) x 8(bx) tiles; XCD key = blockIdx & 7
    const int b  = blockIdx.x;
    const int rg = b & 7, s = b >> 3;
    const int by = (rg >> 1) * 4 + (s >> 3);   // 0..15
    const int bx = (rg & 1) * 8 + (s & 7);     // 0..15

    // staging: wave wid covers tile rows [wid*8, wid*8+8), 64 cols (128 B) per k-step.
    // LDS dest linear (wave base + lane*16); XOR swizzle (byte ^= (row&7)<<4)
    // realized by permuting the GLOBAL source granule: (lane&7) ^ (lane>>3).
    const int srow = wid * 8 + (lane >> 3);
    const int scol = (((lane & 7) ^ (lane >> 3)) << 3);   // elements (granule*8)
    const unsigned short* gA = Wb + (size_t)(by * 64 + srow) * D_DIM + scol;
    const unsigned short* gB = Wb + (size_t)(bx * 64 + srow) * D_DIM + scol;

#define STAGE(bufi, kk)                                                                 \
    do {                                                                                \
        __builtin_amdgcn_global_load_lds(                                               \
            (const __attribute__((address_space(1))) void*)(gA + (kk)),                 \
            (__attribute__((address_space(3))) void*)&smem[bufi][0][wid * 512], 16, 0, 0); \
        __builtin_amdgcn_global_load_lds(                                               \
            (const __attribute__((address_space(1))) void*)(gB + (kk)),                 \
            (__attribute__((address_space(3))) void*)&smem[bufi][1][wid * 512], 16, 0, 0); \
    } while (0)

    f32x4 acc0 = {0.f, 0.f, 0.f, 0.f};
    f32x4 acc1 = {0.f, 0.f, 0.f, 0.f};

    STAGE(0, 0);
    STAGE(1, 64);
    STAGE(2, 128);

    const int arow  = (wm * 16 + l16) * 64;
    const int brow0 = (wn * 32 + l16) * 64;
    const int brow1 = (wn * 32 + 16 + l16) * 64;

    for (int t = 0; t < 32; ++t) {
        // wait own S(t) only; keep deeper prefetches in flight
        if (t < 30)       asm volatile("s_waitcnt vmcnt(4)" ::: "memory");
        else if (t == 30) asm volatile("s_waitcnt vmcnt(2)" ::: "memory");
        else              asm volatile("s_waitcnt vmcnt(0)" ::: "memory");
        __builtin_amdgcn_s_barrier();
        asm volatile("" ::: "memory");

        if (t < 29) STAGE((t + 3) & 3, (t + 3) * 64);   // into slot (t-1)&3: free now

        const unsigned short* Ab = &smem[t & 3][0][0];
        const unsigned short* Bb = &smem[t & 3][1][0];
        s16x8 a[2], b0[2], b1[2];
#pragma unroll
        for (int ks = 0; ks < 2; ++ks) {
            // swizzled read: col-granule (ks*4+quad) ^ (row&7), row&7 == lane&7 here
            const int cs = ((((ks << 2) | quad) ^ (lane & 7)) << 3);
            a[ks]  = *reinterpret_cast<const s16x8*>(Ab + arow  + cs);
            b0[ks] = *reinterpret_cast<const s16x8*>(Bb + brow0 + cs);
            b1[ks] = *reinterpret_cast<const s16x8*>(Bb + brow1 + cs);
        }
#pragma unroll
        for (int ks = 0; ks < 2; ++ks) {
            acc0 = __builtin_amdgcn_mfma_f32_16x16x32_bf16(a[ks], b0[ks], acc0, 0, 0, 0);
            acc1 = __builtin_amdgcn_mfma_f32_16x16x32_bf16(a[ks], b1[ks], acc1, 0, 0, 0);
        }
    }
#undef STAGE

    const float kscale = Kin[0] * 4.4642857142857144f;  // 1/0.224 (DATA_SCALING)

    f32x4 accs[2] = {acc0, acc1};
#pragma unroll
    for (int nt = 0; nt < 2; ++nt) {
#pragma unroll
        for (int r = 0; r < 4; ++r) {
            const int ga = by * 64 + wm * 16 + quad * 4 + r;   // C/D: row = quad*4+reg
            const int gc = bx * 64 + wn * 32 + nt * 16 + l16;  // C/D: col = lane&15
            float d2 = sqw[ga] + sqw[gc] - 2.0f * accs[nt][r];
            dist[(size_t)ga * NPAD + gc] = kscale * sqrtf(fmaxf(d2, 0.f));
        }
    }
}

// Kernel 3: per row of prediction: argmax (lowest-index tie-break) then min ratio
__global__ __launch_bounds__(256) void final_kernel(const float* __restrict__ pred,
                                                    const float* __restrict__ dist,
                                                    float* __restrict__ out) {
    const int row = blockIdx.x;
    const int tid = threadIdx.x;
    const int lane = tid & 63, wid = tid >> 6;
    __shared__ float sp[C_CLS];
    __shared__ float sv[4];
    __shared__ int   si[4];

    const float* p = pred + (size_t)row * C_CLS;
    float v = -INFINITY;
    int bi = 0x7fffffff;
    if (tid < 250) {  // 250*4 = 1000, 16B aligned (row stride 4000 B is 16B-multiple)
        float4 x = *reinterpret_cast<const float4*>(p + tid * 4);
        const int c0 = tid * 4;
        sp[c0 + 0] = x.x; sp[c0 + 1] = x.y; sp[c0 + 2] = x.z; sp[c0 + 3] = x.w;
        v = x.x; bi = c0;
        if (x.y > v) { v = x.y; bi = c0 + 1; }
        if (x.z > v) { v = x.z; bi = c0 + 2; }
        if (x.w > v) { v = x.w; bi = c0 + 3; }
    }
#pragma unroll
    for (int off = 32; off > 0; off >>= 1) {
        float ov = __shfl_down(v, off);
        int   oi = __shfl_down(bi, off);
        if (ov > v || (ov == v && oi < bi)) { v = ov; bi = oi; }
    }
    if (lane == 0) { sv[wid] = v; si[wid] = bi; }
    __syncthreads();
    float y0 = sv[0]; int j0 = si[0];
#pragma unroll
    for (int w = 1; w < 4; ++w) {
        if (sv[w] > y0 || (sv[w] == y0 && si[w] < j0)) { y0 = sv[w]; j0 = si[w]; }
    }

    const float* drow = dist + (size_t)j0 * NPAD;
    float rmin = INFINITY;
    if (tid < 250) {
        const int c0 = tid * 4;
        float4 dv = *reinterpret_cast<const float4*>(drow + c0);
        float4 pv = *reinterpret_cast<const float4*>(&sp[c0]);
        // c==j0: reference uses +inf there; skip component (avoids 0*inf NaN)
        if (c0 + 0 != j0) rmin = fminf(rmin, (y0 - pv.x) * __builtin_amdgcn_rcpf(dv.x));
        if (c0 + 1 != j0) rmin = fminf(rmin, (y0 - pv.y) * __builtin_amdgcn_rcpf(dv.y));
        if (c0 + 2 != j0) rmin = fminf(rmin, (y0 - pv.z) * __builtin_amdgcn_rcpf(dv.z));
        if (c0 + 3 != j0) rmin = fminf(rmin, (y0 - pv.w) * __builtin_amdgcn_rcpf(dv.w));
    }
#pragma unroll
    for (int off = 32; off > 0; off >>= 1) rmin = fminf(rmin, __shfl_down(rmin, off));
    __syncthreads();  // all reads of sv/si for argmax done before reuse
    if (lane == 0) sv[wid] = rmin;
    __syncthreads();
    if (tid == 0) out[row] = fminf(fminf(sv[0], sv[1]), fminf(sv[2], sv[3]));
}

extern "C" void kernel_launch(void* const* d_in, const int* in_sizes, int n_in,
                              void* d_out, int out_size, void* d_ws, size_t ws_size,
                              hipStream_t stream) {
    const float* pred = (const float*)d_in[0];   // (4096, 1000) fp32
    const float* W    = (const float*)d_in[1];   // (1000, 2048) fp32
    const float* K    = (const float*)d_in[2];   // (1,) fp32
    float* out = (float*)d_out;                  // (4096,) fp32

    char* ws = (char*)d_ws;
    unsigned short* Wb = (unsigned short*)ws;                               // 1024*2048*2 = 4 MB
    float* dist = (float*)(ws + (size_t)NPAD * D_DIM * 2);                  // 1024*1024*4 = 4 MB
    float* sqw  = (float*)(ws + (size_t)NPAD * D_DIM * 2 + (size_t)NPAD * NPAD * 4); // 4 KB

    prep_kernel<<<NPAD, 256, 0, stream>>>(W, Wb, sqw);
    dist_kernel<<<dim3(256), 512, 0, stream>>>(Wb, sqw, K, dist);
    final_kernel<<<B_ROWS, 256, 0, stream>>>(pred, dist, out);
}